// Round 5
// baseline (605.931 us; speedup 1.0000x reference)
//
#include <hip/hip_runtime.h>
#include <hip/hip_bf16.h>

#define BB 8
#define TT 8192
#define HH 16
#define HDIM 64
#define DDIM 1024
#define NS 8            /* splits per (b,h) */
#define TSPLIT 1024     /* positions per split */

// idx may arrive as int64 or int32; detect by high-word probe (values < 8192).
__device__ __forceinline__ int load_idx(const int* __restrict__ idx, int b) {
  const bool wide = (idx[1] == 0) && (idx[3] == 0) && (idx[5] == 0) && (idx[7] == 0);
  int v = wide ? idx[2 * b] : idx[b];
  return min(max(v, 0), TT - 1);   // defensive clamp: never OOB
}

// ---------------------------------------------------------------------------
// Kernel A: qkv = x @ W_attn + b_attn.  One thread per (b, j) of [8, 3072].
// All fp32. q scaled by 1/8 -> ws; k_step/v_step -> ws + out (fp32).
// ---------------------------------------------------------------------------
__global__ __launch_bounds__(256) void qkv_kernel(
    const float* __restrict__ x, const float* __restrict__ W,
    const float* __restrict__ bias,
    float* __restrict__ q_ws, float* __restrict__ kstep_ws,
    float* __restrict__ vstep_ws, float* __restrict__ out)
{
  __shared__ float x_s[DDIM];
  const int tid = threadIdx.x;
  const int g = blockIdx.x * 256 + tid;
  const int b = g / 3072;          // block-uniform (3072 % 256 == 0)
  const int j = g % 3072;

  const float* xrow = x + b * DDIM;
  for (int i = tid; i < DDIM; i += 256) x_s[i] = xrow[i];
  __syncthreads();

  const float* wp = W + j;
  float a0 = 0.f, a1 = 0.f, a2 = 0.f, a3 = 0.f;
  #pragma unroll 4
  for (int dd = 0; dd < DDIM; dd += 4) {
    a0 += x_s[dd + 0] * wp[(size_t)(dd + 0) * 3072];
    a1 += x_s[dd + 1] * wp[(size_t)(dd + 1) * 3072];
    a2 += x_s[dd + 2] * wp[(size_t)(dd + 2) * 3072];
    a3 += x_s[dd + 3] * wp[(size_t)(dd + 3) * 3072];
  }
  float acc = (a0 + a1) + (a2 + a3) + bias[j];

  if (j < 1024) {
    q_ws[b * DDIM + j] = acc * 0.125f;  // 1/sqrt(64)
  } else if (j < 2048) {
    int jj = j - 1024;
    kstep_ws[b * DDIM + jj] = acc;
    out[8192 + b * DDIM + jj] = acc;    // output 1: k_step (fp32)
  } else {
    int jj = j - 2048;
    vstep_ws[b * DDIM + jj] = acc;
    out[16384 + b * DDIM + jj] = acc;   // output 2: v_step (fp32)
  }
}

// ---------------------------------------------------------------------------
// Kernel B: flash-decode partial. Block = (b, h, split s) over TSPLIT=1024
// positions for ONE head. Substitutes k_step/v_step at t == idx[b]; masks
// t > idx[b]. Writes per-(b,h,s): m, l, o[64] (unnormalized).
// ---------------------------------------------------------------------------
__global__ __launch_bounds__(256) void attn_partial_kernel(
    const float* __restrict__ past_k, const float* __restrict__ past_v,
    const int* __restrict__ idx,
    const float* __restrict__ q_ws, const float* __restrict__ kstep_ws,
    const float* __restrict__ vstep_ws,
    float* __restrict__ part_m, float* __restrict__ part_l,
    float* __restrict__ part_o)
{
  const int tid = threadIdx.x;
  const int s  = blockIdx.x & (NS - 1);
  const int h  = (blockIdx.x >> 3) & (HH - 1);
  const int b  = blockIdx.x >> 7;
  const int idxb = load_idx(idx, b);
  const int t0 = s * TSPLIT;
  const int bhs = (b * HH + h) * NS + s;

  if (t0 > idxb) {   // whole split masked (uniform branch, before any barrier)
    if (tid == 0) { part_m[bhs] = -1e30f; part_l[bhs] = 0.f; }
    return;
  }
  const int nvalid = min(TSPLIT, idxb - t0 + 1);

  __shared__ float q_s[HDIM];
  __shared__ float p_s[TSPLIT];
  __shared__ float red_s[256];
  __shared__ float o_s[16 * HDIM];

  if (tid < HDIM) q_s[tid] = q_ws[b * DDIM + h * HDIM + tid];
  __syncthreads();

  // ---- phase 1: scores, 4 positions per thread (t_local = tid + i*256) ----
  float sc[4];
  const float* Kb = past_k + (((size_t)b * TT + t0) * HH + h) * HDIM;
  #pragma unroll
  for (int i = 0; i < 4; ++i) {
    const int tl = tid + i * 256;
    float v;
    if (tl >= nvalid) {
      v = -1e30f;
    } else if (t0 + tl == idxb) {
      const float* kr = kstep_ws + b * DDIM + h * HDIM;
      float acc = 0.f;
      #pragma unroll
      for (int d = 0; d < HDIM; ++d) acc += q_s[d] * kr[d];
      v = acc;
    } else {
      const float4* kr = (const float4*)(Kb + (size_t)tl * (HH * HDIM));
      float a0 = 0.f, a1 = 0.f, a2 = 0.f, a3 = 0.f;
      #pragma unroll
      for (int seg = 0; seg < 16; ++seg) {
        float4 u = kr[seg];
        a0 += q_s[seg * 4 + 0] * u.x;
        a1 += q_s[seg * 4 + 1] * u.y;
        a2 += q_s[seg * 4 + 2] * u.z;
        a3 += q_s[seg * 4 + 3] * u.w;
      }
      v = (a0 + a1) + (a2 + a3);
    }
    sc[i] = v;
  }

  // ---- phase 2: block max, exp, block sum ----
  float lmax = fmaxf(fmaxf(sc[0], sc[1]), fmaxf(sc[2], sc[3]));
  red_s[tid] = lmax;
  __syncthreads();
  for (int st = 128; st > 0; st >>= 1) {
    if (tid < st) red_s[tid] = fmaxf(red_s[tid], red_s[tid + st]);
    __syncthreads();
  }
  const float mh = red_s[0];
  __syncthreads();                 // before red_s reuse

  float lsum = 0.f;
  #pragma unroll
  for (int i = 0; i < 4; ++i) {
    float p = __expf(sc[i] - mh);  // masked rows: exp(-1e30 - mh) -> 0
    p_s[tid + i * 256] = p;
    lsum += p;
  }
  red_s[tid] = lsum;
  __syncthreads();
  for (int st = 128; st > 0; st >>= 1) {
    if (tid < st) red_s[tid] += red_s[tid + st];
    __syncthreads();
  }
  if (tid == 0) { part_m[bhs] = mh; part_l[bhs] = red_s[0]; }
  // p_s writes are covered by the sum-reduction barriers.

  // ---- phase 3: o[d] = sum_t p[t] * V[t][d]; thread = (t-stripe, d-quad) ---
  const int tg = tid >> 4;          // 0..15  t-stripe
  const int d0 = (tid & 15) * 4;    // 0..60  d-quad
  float a0 = 0.f, a1 = 0.f, a2 = 0.f, a3 = 0.f;
  const float* Vb = past_v + (((size_t)b * TT + t0) * HH + h) * HDIM;
  for (int tl = tg; tl < nvalid; tl += 16) {
    const float p = p_s[tl];
    if (t0 + tl == idxb) {
      const float* vr = vstep_ws + b * DDIM + h * HDIM + d0;
      a0 += p * vr[0]; a1 += p * vr[1]; a2 += p * vr[2]; a3 += p * vr[3];
    } else {
      const float4 u = *(const float4*)(Vb + (size_t)tl * (HH * HDIM) + d0);
      a0 += p * u.x; a1 += p * u.y; a2 += p * u.z; a3 += p * u.w;
    }
  }
  o_s[tg * HDIM + d0 + 0] = a0;
  o_s[tg * HDIM + d0 + 1] = a1;
  o_s[tg * HDIM + d0 + 2] = a2;
  o_s[tg * HDIM + d0 + 3] = a3;
  __syncthreads();
  if (tid < HDIM) {
    float acc = 0.f;
    #pragma unroll
    for (int g2 = 0; g2 < 16; ++g2) acc += o_s[g2 * HDIM + tid];
    part_o[(size_t)bhs * HDIM + tid] = acc;
  }
}

// ---------------------------------------------------------------------------
// Kernel C: combine NS split partials per (b,h). 128 blocks x 64 lanes.
// ---------------------------------------------------------------------------
__global__ __launch_bounds__(64) void attn_combine_kernel(
    const float* __restrict__ part_m, const float* __restrict__ part_l,
    const float* __restrict__ part_o, float* __restrict__ y_ws)
{
  const int bh = blockIdx.x;
  const int lane = threadIdx.x;

  float m[NS], l[NS];
  float M = -1e30f;
  #pragma unroll
  for (int s = 0; s < NS; ++s) {
    m[s] = part_m[bh * NS + s];
    l[s] = part_l[bh * NS + s];
    M = fmaxf(M, m[s]);
  }
  float L = 0.f, acc = 0.f;
  #pragma unroll
  for (int s = 0; s < NS; ++s) {
    float w = (l[s] > 0.f) ? __expf(m[s] - M) : 0.f;
    if (w > 0.f) {    // skip inactive splits: their part_o is poison
      L += l[s] * w;
      acc += w * part_o[(size_t)(bh * NS + s) * HDIM + lane];
    }
  }
  y_ws[bh * HDIM + lane] = (L > 0.f) ? (acc / L) : 0.f;
}

// ---------------------------------------------------------------------------
// Kernel D: out_y = y @ W_proj + b_proj. One thread per (b, j). 32 blocks.
// ---------------------------------------------------------------------------
__global__ __launch_bounds__(256) void proj_kernel(
    const float* __restrict__ y_ws, const float* __restrict__ W,
    const float* __restrict__ bias, float* __restrict__ out)
{
  __shared__ float y_s[DDIM];
  const int tid = threadIdx.x;
  const int g = blockIdx.x * 256 + tid;
  const int b = g >> 10;           // block-uniform
  const int j = g & 1023;

  const float* yrow = y_ws + b * DDIM;
  for (int i = tid; i < DDIM; i += 256) y_s[i] = yrow[i];
  __syncthreads();

  const float* wp = W + j;
  float a0 = 0.f, a1 = 0.f, a2 = 0.f, a3 = 0.f;
  #pragma unroll 4
  for (int dd = 0; dd < DDIM; dd += 4) {
    a0 += y_s[dd + 0] * wp[(size_t)(dd + 0) * DDIM];
    a1 += y_s[dd + 1] * wp[(size_t)(dd + 1) * DDIM];
    a2 += y_s[dd + 2] * wp[(size_t)(dd + 2) * DDIM];
    a3 += y_s[dd + 3] * wp[(size_t)(dd + 3) * DDIM];
  }
  float acc = (a0 + a1) + (a2 + a3) + bias[j];
  out[b * DDIM + j] = acc;         // output 0: y (fp32)
}

// ---------------------------------------------------------------------------
// Workspace layout (floats):  total = 100352 floats = 392 KB
//   q_ws     [    0 ..  8192)
//   kstep_ws [ 8192 .. 16384)
//   vstep_ws [16384 .. 24576)
//   y_ws     [24576 .. 32768)
//   part_m   [32768 .. 33792)   B*H*NS = 1024
//   part_l   [33792 .. 34816)
//   part_o   [34816 ..100352)   B*H*NS*HDIM = 65536
// ---------------------------------------------------------------------------
extern "C" void kernel_launch(void* const* d_in, const int* in_sizes, int n_in,
                              void* d_out, int out_size, void* d_ws, size_t ws_size,
                              hipStream_t stream) {
  const float* x      = (const float*)d_in[0];
  const float* past_k = (const float*)d_in[1];
  const float* past_v = (const float*)d_in[2];
  const int*   idx    = (const int*)  d_in[3];
  const float* W_attn = (const float*)d_in[4];
  const float* b_attn = (const float*)d_in[5];
  const float* W_proj = (const float*)d_in[6];
  const float* b_proj = (const float*)d_in[7];
  float* out = (float*)d_out;

  float* ws       = (float*)d_ws;
  float* q_ws     = ws;
  float* kstep_ws = ws + 8192;
  float* vstep_ws = ws + 16384;
  float* y_ws     = ws + 24576;
  float* part_m   = ws + 32768;
  float* part_l   = ws + 33792;
  float* part_o   = ws + 34816;

  qkv_kernel<<<dim3(96), dim3(256), 0, stream>>>(
      x, W_attn, b_attn, q_ws, kstep_ws, vstep_ws, out);
  attn_partial_kernel<<<dim3(BB * HH * NS), dim3(256), 0, stream>>>(
      past_k, past_v, idx, q_ws, kstep_ws, vstep_ws, part_m, part_l, part_o);
  attn_combine_kernel<<<dim3(BB * HH), dim3(64), 0, stream>>>(
      part_m, part_l, part_o, y_ws);
  proj_kernel<<<dim3(32), dim3(256), 0, stream>>>(
      y_ws, W_proj, b_proj, out);
}